// Round 1
// baseline (166.702 us; speedup 1.0000x reference)
//
#include <hip/hip_runtime.h>
#include <hip/hip_bf16.h>

#define EPSV 1e-8f

// ---------------------------------------------------------------------------
// Kernel 1: Householder QR of W = [weight | pose_weight] + EPS  (512 x 26),
// replicating LAPACK sgeqrf sign conventions (beta = -sign(alpha)*norm),
// then Q = W * R^{-1}, stored transposed as qt[26][512] in workspace.
// Single block, 512 threads (thread i owns row i; A lives in LDS).
// ---------------------------------------------------------------------------

__device__ __forceinline__ float block_sum_512(float v, volatile float* red) {
#pragma unroll
    for (int o = 32; o > 0; o >>= 1) v += __shfl_xor(v, o);
    const int lane = threadIdx.x & 63;
    const int wid  = threadIdx.x >> 6;
    if (lane == 0) red[wid] = v;
    __syncthreads();
    float s = red[0] + red[1] + red[2] + red[3] + red[4] + red[5] + red[6] + red[7];
    __syncthreads();
    return s;
}

__global__ __launch_bounds__(512) void qr_kernel(const float* __restrict__ pose_w,
                                                 const float* __restrict__ lip_w,
                                                 float* __restrict__ qt) {
    __shared__ float A[512 * 27];     // row-major, padded stride 27 (bank-friendly)
    __shared__ float Rinv[26 * 26];
    __shared__ float dcol[26];
    __shared__ float red[8];

    const int i    = threadIdx.x;     // row
    const int lane = i & 63;
    const int wid  = i >> 6;

    // Load W row i (concat order: weight[20] then pose_weight[6]) + EPS.
#pragma unroll
    for (int m = 0; m < 20; ++m) A[i * 27 + m] = lip_w[i * 20 + m] + EPSV;
#pragma unroll
    for (int m = 0; m < 6; ++m)  A[i * 27 + 20 + m] = pose_w[i * 6 + m] + EPSV;
    __syncthreads();

    // 26 sequential Householder steps. Rows 0..j-1 hold finished R rows.
    for (int j = 0; j < 26; ++j) {
        const float xi    = (i >= j) ? A[i * 27 + j] : 0.f;
        const float sigma = block_sum_512(xi * xi, red);   // alpha^2 + ||x_sub||^2
        const float alpha = A[j * 27 + j];
        const float normx = sqrtf(sigma);
        // LAPACK slarfg: beta = -sign(alpha) * norm
        const float beta  = (alpha >= 0.f) ? -normx : normx;
        const float tau   = (beta - alpha) / beta;
        const float denom = alpha - beta;                  // |denom| >= norm, safe
        const float vi    = (i == j) ? 1.f : ((i > j) ? xi / denom : 0.f);
        __syncthreads();   // all reads of alpha / column j complete
        if (i >= j) A[i * 27 + j] = vi;   // stash v in column j (rows >= j only)
        __syncthreads();

        // d_c = v^T A[:,c] for c > j; columns round-robin across the 8 waves.
        for (int c = j + 1 + wid; c < 26; c += 8) {
            float p = 0.f;
            for (int rr = lane; rr < 512; rr += 64)
                if (rr >= j) p += A[rr * 27 + j] * A[rr * 27 + c];
#pragma unroll
            for (int o = 32; o > 0; o >>= 1) p += __shfl_xor(p, o);
            if (lane == 0) dcol[c] = p;
        }
        __syncthreads();

        // A := A - tau * v * d^T  (only rows >= j are touched by the reflector)
        if (i >= j) {
            for (int c = j + 1; c < 26; ++c)
                A[i * 27 + c] -= tau * dcol[c] * vi;
        }
        if (i == j) A[j * 27 + j] = beta;   // R diagonal
        __syncthreads();
    }

    // R^{-1} by back-substitution; thread c solves column c (independent).
    if (i < 26) {
        const int c = i;
        for (int k = c; k >= 0; --k) {
            float s = (k == c) ? 1.f : 0.f;
            for (int m = k + 1; m <= c; ++m) s -= A[k * 27 + m] * Rinv[m * 26 + c];
            Rinv[k * 26 + c] = s / A[k * 27 + k];
        }
    }
    __syncthreads();

    // Q = W * Rinv (W reloaded from global; A's lower part was destroyed).
    // Store transposed: qt[k*512 + i] = Q[i][k]. Rinv upper-triangular => m <= k.
    float wrow[26];
#pragma unroll
    for (int m = 0; m < 20; ++m) wrow[m] = lip_w[i * 20 + m] + EPSV;
#pragma unroll
    for (int m = 0; m < 6; ++m)  wrow[20 + m] = pose_w[i * 6 + m] + EPSV;
#pragma unroll
    for (int k = 0; k < 26; ++k) {
        float q = 0.f;
#pragma unroll
        for (int m = 0; m < 26; ++m)
            if (m <= k) q = fmaf(wrow[m], Rinv[m * 26 + k], q);
        qt[k * 512 + i] = q;
    }
}

// ---------------------------------------------------------------------------
// Kernel 2: out[B][512] = input[B][26] @ qt^T   (qt is [26][512])
// Block = 256 threads handles 32 rows x 512 cols. Q fragment (26 x float4)
// in registers; input tile staged in LDS (broadcast reads); float4 stores.
// ---------------------------------------------------------------------------

__global__ __launch_bounds__(256) void out_gemm(const float* __restrict__ in,
                                                const float* __restrict__ qt,
                                                float* __restrict__ out) {
    __shared__ float xs[32][28];      // padded stride (16B-aligned rows)
    const int tid = threadIdx.x;
    const long base = (long)blockIdx.x * 32;

    // Cooperative load of 32x26 input tile (832 contiguous floats).
    const float* ip = in + base * 26;
    for (int idx = tid; idx < 832; idx += 256)
        xs[idx / 26][idx % 26] = ip[idx];

    const int cg = tid & 127;         // column group: cols 4*cg .. 4*cg+3
    const int rh = tid >> 7;          // row half: 0 or 1

    float4 qf[26];
#pragma unroll
    for (int k = 0; k < 26; ++k)
        qf[k] = *reinterpret_cast<const float4*>(qt + k * 512 + cg * 4);
    __syncthreads();

    float* op = out + (base + (long)rh * 16) * 512 + cg * 4;
#pragma unroll
    for (int r = 0; r < 16; ++r) {
        const int rl = rh * 16 + r;
        float ax = 0.f, ay = 0.f, az = 0.f, aw = 0.f;
#pragma unroll
        for (int k = 0; k < 26; ++k) {
            const float x = xs[rl][k];
            ax = fmaf(x, qf[k].x, ax);
            ay = fmaf(x, qf[k].y, ay);
            az = fmaf(x, qf[k].z, az);
            aw = fmaf(x, qf[k].w, aw);
        }
        float4 o = make_float4(ax, ay, az, aw);
        *reinterpret_cast<float4*>(op + (long)r * 512) = o;
    }
}

// ---------------------------------------------------------------------------

extern "C" void kernel_launch(void* const* d_in, const int* in_sizes, int n_in,
                              void* d_out, int out_size, void* d_ws, size_t ws_size,
                              hipStream_t stream) {
    const float* input  = (const float*)d_in[0];   // (B, 26)
    const float* pose_w = (const float*)d_in[1];   // (512, 6)
    const float* lip_w  = (const float*)d_in[2];   // (512, 20)
    float* out = (float*)d_out;                    // (B, 512)
    float* qt  = (float*)d_ws;                     // Q^T as [26][512] f32

    const int B = in_sizes[0] / 26;

    qr_kernel<<<1, 512, 0, stream>>>(pose_w, lip_w, qt);
    out_gemm<<<(B + 31) / 32, 256, 0, stream>>>(input, qt, out);
}